// Round 1
// baseline (5417.952 us; speedup 1.0000x reference)
//
#include <hip/hip_runtime.h>
#include <math.h>

#define NN 50000
#define NE 400000

// ---------------- degree / dinv ----------------
__global__ void init_deg(float* deg, int n) {
    int i = blockIdx.x * blockDim.x + threadIdx.x;
    if (i < n) deg[i] = 1.0f;
}
__global__ void edge_deg(const int* __restrict__ dst, float* deg, int E) {
    int e = blockIdx.x * blockDim.x + threadIdx.x;
    if (e < E) atomicAdd(&deg[dst[e]], 1.0f);
}
__global__ void make_dinv(float* deg, int n) {
    int i = blockIdx.x * blockDim.x + threadIdx.x;
    if (i < n) deg[i] = rsqrtf(deg[i]);
}

// ---------------- fused GEMM: H = act(X) @ W ; Ainit = H*dinv^2 + b --------
// BM=64, BN=64, BK=16, 256 threads, 4x4 per thread.
template <int RELU_IN>
__global__ __launch_bounds__(256) void gemm_fused(
    const float* __restrict__ X, const float* __restrict__ W,
    const float* __restrict__ bias, const float* __restrict__ dinv,
    float* __restrict__ H, float* __restrict__ Ainit,
    int N, int K, int NO)
{
    __shared__ float As[16][64];
    __shared__ float Bs[16][64];
    const int tid = threadIdx.x;
    const int m0 = blockIdx.x * 64;
    const int n0 = blockIdx.y * 64;
    const int ty = tid >> 4;   // 0..15
    const int tx = tid & 15;   // 0..15

    // load mapping
    const int lr = tid >> 2;          // 0..63 : row in X tile
    const int lc = (tid & 3) << 2;    // 0,4,8,12 : k offset
    const int wr = tid >> 4;          // 0..15 : k row in W tile
    const int wc = (tid & 15) << 2;   // 0..60 : col in W tile

    float acc[4][4] = {};

    for (int k0 = 0; k0 < K; k0 += 16) {
        float4 xv = make_float4(0.f, 0.f, 0.f, 0.f);
        const int xr = m0 + lr;
        if (xr < N)
            xv = *reinterpret_cast<const float4*>(X + (size_t)xr * K + k0 + lc);
        if (RELU_IN) {
            xv.x = fmaxf(xv.x, 0.f); xv.y = fmaxf(xv.y, 0.f);
            xv.z = fmaxf(xv.z, 0.f); xv.w = fmaxf(xv.w, 0.f);
        }
        As[lc + 0][lr] = xv.x; As[lc + 1][lr] = xv.y;
        As[lc + 2][lr] = xv.z; As[lc + 3][lr] = xv.w;

        const float4 wv = *reinterpret_cast<const float4*>(
            W + (size_t)(k0 + wr) * NO + n0 + wc);
        *reinterpret_cast<float4*>(&Bs[wr][wc]) = wv;

        __syncthreads();
        #pragma unroll
        for (int k = 0; k < 16; ++k) {
            float a[4], b[4];
            #pragma unroll
            for (int i = 0; i < 4; ++i) a[i] = As[k][ty * 4 + i];
            #pragma unroll
            for (int j = 0; j < 4; ++j) b[j] = Bs[k][tx * 4 + j];
            #pragma unroll
            for (int i = 0; i < 4; ++i)
                #pragma unroll
                for (int j = 0; j < 4; ++j)
                    acc[i][j] = fmaf(a[i], b[j], acc[i][j]);
        }
        __syncthreads();
    }

    const int col0 = n0 + tx * 4;
    const float4 bv = *reinterpret_cast<const float4*>(bias + col0);
    #pragma unroll
    for (int i = 0; i < 4; ++i) {
        const int row = m0 + ty * 4 + i;
        if (row >= N) break;
        const float di = dinv[row];
        const float di2 = di * di;
        float4 hv = make_float4(acc[i][0], acc[i][1], acc[i][2], acc[i][3]);
        *reinterpret_cast<float4*>(H + (size_t)row * NO + col0) = hv;
        float4 av;
        av.x = fmaf(hv.x, di2, bv.x);
        av.y = fmaf(hv.y, di2, bv.y);
        av.z = fmaf(hv.z, di2, bv.z);
        av.w = fmaf(hv.w, di2, bv.w);
        *reinterpret_cast<float4*>(Ainit + (size_t)row * NO + col0) = av;
    }
}

// ---------------- edge scatter: A[dst] += H[src] * dinv[src]*dinv[dst] -----
__global__ void scatter_edges(const float* __restrict__ H,
                              const int* __restrict__ src,
                              const int* __restrict__ dst,
                              const float* __restrict__ dinv,
                              float* __restrict__ A,
                              int E, int lgF4, int F)
{
    const size_t idx = (size_t)blockIdx.x * blockDim.x + threadIdx.x;
    const size_t total = (size_t)E << lgF4;
    if (idx >= total) return;
    const int F4m1 = (1 << lgF4) - 1;
    const int e  = (int)(idx >> lgF4);
    const int f4 = (int)(idx & F4m1);
    const int s = src[e], d = dst[e];
    const float coef = dinv[s] * dinv[d];
    const float4 v = *reinterpret_cast<const float4*>(H + (size_t)s * F + f4 * 4);
    float* out = A + (size_t)d * F + f4 * 4;
    atomicAdd(out + 0, v.x * coef);
    atomicAdd(out + 1, v.y * coef);
    atomicAdd(out + 2, v.z * coef);
    atomicAdd(out + 3, v.w * coef);
}

// ---------------- epilogue ----------------
__global__ void zero_one(float* p) { *p = 0.f; }

__global__ void relu_sum(float* __restrict__ Z, float* __restrict__ S, int total) {
    const size_t stride = (size_t)gridDim.x * blockDim.x;
    float local = 0.f;
    for (size_t idx = (size_t)blockIdx.x * blockDim.x + threadIdx.x;
         idx < (size_t)total; idx += stride) {
        float z = Z[idx];
        z = fmaxf(z, 0.f);
        Z[idx] = z;
        local += z;
    }
    #pragma unroll
    for (int off = 32; off; off >>= 1) local += __shfl_down(local, off);
    if ((threadIdx.x & 63) == 0) atomicAdd(S, local);
}

// one wave per row of 128
__global__ void final_norm(float* __restrict__ Z, const float* __restrict__ S, int N) {
    const int wid = threadIdx.x >> 6;
    const int lane = threadIdx.x & 63;
    const int row = blockIdx.x * 4 + wid;
    if (row >= N) return;
    const float inv = 1.0f / (*S);
    float v0 = Z[(size_t)row * 128 + lane] * inv;
    float v1 = Z[(size_t)row * 128 + lane + 64] * inv;
    const float t0 = tanhf(v0), t1 = tanhf(v1);
    const float y0 = t0 * t0, y1 = t1 * t1;
    float ss = y0 * y0 + y1 * y1;
    #pragma unroll
    for (int off = 32; off; off >>= 1) ss += __shfl_xor(ss, off);
    const float nrm = fmaxf(sqrtf(ss), 1e-12f);
    const float innrm = 1.0f / nrm;
    Z[(size_t)row * 128 + lane]      = y0 * innrm;
    Z[(size_t)row * 128 + lane + 64] = y1 * innrm;
}

extern "C" void kernel_launch(void* const* d_in, const int* in_sizes, int n_in,
                              void* d_out, int out_size, void* d_ws, size_t ws_size,
                              hipStream_t stream) {
    const float* x  = (const float*)d_in[0];
    const int*   ei = (const int*)d_in[1];
    const float* W1 = (const float*)d_in[2];
    const float* b1 = (const float*)d_in[3];
    const float* W2 = (const float*)d_in[4];
    const float* b2 = (const float*)d_in[5];
    const float* W3 = (const float*)d_in[6];
    const float* b3 = (const float*)d_in[7];
    float* out = (float*)d_out;

    const int N = NN, E = NE;
    const int* src = ei;
    const int* dst = ei + E;

    char* ws = (char*)d_ws;
    float* dinv = (float*)ws;                              // N floats
    float* Ssum = (float*)(ws + 256 * 1024);               // 1 float
    float* Hbuf = (float*)(ws + (1 << 20));                // N*512 floats
    float* Abuf = (float*)(ws + (1 << 20) + (size_t)N * 512 * 4);  // N*512 floats

    // degrees -> dinv
    init_deg<<<(N + 255) / 256, 256, 0, stream>>>(dinv, N);
    edge_deg<<<(E + 255) / 256, 256, 0, stream>>>(dst, dinv, E);
    make_dinv<<<(N + 255) / 256, 256, 0, stream>>>(dinv, N);

    // ---- layer 1: x[ N x512 ] @ W1[512x512] ----
    {
        dim3 g((N + 63) / 64, 512 / 64);
        gemm_fused<0><<<g, 256, 0, stream>>>(x, W1, b1, dinv, Hbuf, Abuf, N, 512, 512);
        size_t tot = (size_t)E * (512 / 4);
        scatter_edges<<<(tot + 255) / 256, 256, 0, stream>>>(Hbuf, src, dst, dinv, Abuf, E, 7, 512);
    }
    // ---- layer 2: relu(A1)[Nx512] @ W2[512x256] ; H2/A2 packed in Hbuf ----
    float* H2 = Hbuf;
    float* A2 = Hbuf + (size_t)N * 256;
    {
        dim3 g((N + 63) / 64, 256 / 64);
        gemm_fused<1><<<g, 256, 0, stream>>>(Abuf, W2, b2, dinv, H2, A2, N, 512, 256);
        size_t tot = (size_t)E * (256 / 4);
        scatter_edges<<<(tot + 255) / 256, 256, 0, stream>>>(H2, src, dst, dinv, A2, E, 6, 256);
    }
    // ---- layer 3: relu(A2)[Nx256] @ W3[256x128] ; H3 in Abuf, A3 in d_out ----
    {
        dim3 g((N + 63) / 64, 128 / 64);
        gemm_fused<1><<<g, 256, 0, stream>>>(A2, W3, b3, dinv, Abuf, out, N, 256, 128);
        size_t tot = (size_t)E * (128 / 4);
        scatter_edges<<<(tot + 255) / 256, 256, 0, stream>>>(Abuf, src, dst, dinv, out, E, 5, 128);
    }
    // ---- epilogue ----
    zero_one<<<1, 1, 0, stream>>>(Ssum);
    relu_sum<<<2048, 256, 0, stream>>>(out, Ssum, N * 128);
    final_norm<<<(N + 3) / 4, 256, 0, stream>>>(out, Ssum, N);
}

// Round 2
// 1120.490 us; speedup vs baseline: 4.8353x; 4.8353x over previous
//
#include <hip/hip_runtime.h>
#include <math.h>

#define NN 50000
#define NE 400000

// ---------------- degree histogram / dinv ----------------
__global__ void zero_int(int* p, int n) {
    int i = blockIdx.x * blockDim.x + threadIdx.x;
    if (i < n) p[i] = 0;
}
__global__ void edge_hist(const int* __restrict__ dst, int* __restrict__ deg, int E) {
    int e = blockIdx.x * blockDim.x + threadIdx.x;
    if (e < E) atomicAdd(&deg[dst[e]], 1);
}
__global__ void make_dinv(const int* __restrict__ deg, float* __restrict__ dinv, int n) {
    int i = blockIdx.x * blockDim.x + threadIdx.x;
    if (i < n) dinv[i] = rsqrtf(1.0f + (float)deg[i]);
}

// ---------------- prefix sum (single block, 1024 thr) ----------------
__global__ __launch_bounds__(1024) void scan_deg(const int* __restrict__ deg,
                                                 int* __restrict__ rowptr,
                                                 int* __restrict__ cursor, int N) {
    __shared__ int sd[1024];
    __shared__ int carry;
    if (threadIdx.x == 0) carry = 0;
    __syncthreads();
    for (int base = 0; base < N; base += 1024) {
        const int i = base + threadIdx.x;
        const int v = (i < N) ? deg[i] : 0;
        sd[threadIdx.x] = v;
        __syncthreads();
        for (int off = 1; off < 1024; off <<= 1) {
            int t = (threadIdx.x >= off) ? sd[threadIdx.x - off] : 0;
            __syncthreads();
            sd[threadIdx.x] += t;
            __syncthreads();
        }
        const int excl = carry + sd[threadIdx.x] - v;
        if (i < N) { rowptr[i] = excl; cursor[i] = excl; }
        __syncthreads();
        if (threadIdx.x == 1023) carry += sd[1023];
        __syncthreads();
    }
    if (threadIdx.x == 0) rowptr[N] = carry;
}

__global__ void build_csr(const int* __restrict__ src, const int* __restrict__ dst,
                          int* __restrict__ cursor, int* __restrict__ csr_src, int E) {
    int e = blockIdx.x * blockDim.x + threadIdx.x;
    if (e < E) {
        int pos = atomicAdd(&cursor[dst[e]], 1);
        csr_src[pos] = src[e];
    }
}

// ---------------- GEMM: H = act(X) @ W ----------------
// BM=64, BN=64, BK=16, 256 threads, 4x4 per thread.
template <int RELU_IN>
__global__ __launch_bounds__(256) void gemm_k(
    const float* __restrict__ X, const float* __restrict__ W,
    float* __restrict__ H, int N, int K, int NO)
{
    __shared__ float As[16][64];
    __shared__ float Bs[16][64];
    const int tid = threadIdx.x;
    const int m0 = blockIdx.x * 64;
    const int n0 = blockIdx.y * 64;
    const int ty = tid >> 4;
    const int tx = tid & 15;

    const int lr = tid >> 2;
    const int lc = (tid & 3) << 2;
    const int wr = tid >> 4;
    const int wc = (tid & 15) << 2;

    float acc[4][4] = {};

    for (int k0 = 0; k0 < K; k0 += 16) {
        float4 xv = make_float4(0.f, 0.f, 0.f, 0.f);
        const int xr = m0 + lr;
        if (xr < N)
            xv = *reinterpret_cast<const float4*>(X + (size_t)xr * K + k0 + lc);
        if (RELU_IN) {
            xv.x = fmaxf(xv.x, 0.f); xv.y = fmaxf(xv.y, 0.f);
            xv.z = fmaxf(xv.z, 0.f); xv.w = fmaxf(xv.w, 0.f);
        }
        As[lc + 0][lr] = xv.x; As[lc + 1][lr] = xv.y;
        As[lc + 2][lr] = xv.z; As[lc + 3][lr] = xv.w;

        const float4 wv = *reinterpret_cast<const float4*>(
            W + (size_t)(k0 + wr) * NO + n0 + wc);
        *reinterpret_cast<float4*>(&Bs[wr][wc]) = wv;

        __syncthreads();
        #pragma unroll
        for (int k = 0; k < 16; ++k) {
            float a[4], b[4];
            #pragma unroll
            for (int i = 0; i < 4; ++i) a[i] = As[k][ty * 4 + i];
            #pragma unroll
            for (int j = 0; j < 4; ++j) b[j] = Bs[k][tx * 4 + j];
            #pragma unroll
            for (int i = 0; i < 4; ++i)
                #pragma unroll
                for (int j = 0; j < 4; ++j)
                    acc[i][j] = fmaf(a[i], b[j], acc[i][j]);
        }
        __syncthreads();
    }

    const int col0 = n0 + tx * 4;
    #pragma unroll
    for (int i = 0; i < 4; ++i) {
        const int row = m0 + ty * 4 + i;
        if (row >= N) break;
        float4 hv = make_float4(acc[i][0], acc[i][1], acc[i][2], acc[i][3]);
        *reinterpret_cast<float4*>(H + (size_t)row * NO + col0) = hv;
    }
}

// ---------------- CSR pull-aggregate ----------------
// A[d] = dinv[d]*(sum_in dinv[s]*H[s]) + dinv[d]^2*H[d] + bias
// LPN lanes cooperate on one node; each lane owns F/(4*LPN) float4 chunks.
template <int F, int LPN>
__global__ __launch_bounds__(256) void aggregate(
    const float* __restrict__ H, const int* __restrict__ rowptr,
    const int* __restrict__ csr_src, const float* __restrict__ dinv,
    const float* __restrict__ bias, float* __restrict__ A, int N)
{
    constexpr int F4PL = F / (4 * LPN);
    const int gtid = blockIdx.x * blockDim.x + threadIdx.x;
    const int node = gtid / LPN;
    const int lane = gtid % LPN;
    if (node >= N) return;

    float4 acc[F4PL];
    #pragma unroll
    for (int c = 0; c < F4PL; ++c) acc[c] = make_float4(0.f, 0.f, 0.f, 0.f);

    const int beg = rowptr[node];
    const int end = rowptr[node + 1];
    for (int j = beg; j < end; ++j) {
        const int s = csr_src[j];
        const float ds = dinv[s];
        const float4* hp = reinterpret_cast<const float4*>(H + (size_t)s * F);
        #pragma unroll
        for (int c = 0; c < F4PL; ++c) {
            const float4 v = hp[lane + c * LPN];
            acc[c].x = fmaf(v.x, ds, acc[c].x);
            acc[c].y = fmaf(v.y, ds, acc[c].y);
            acc[c].z = fmaf(v.z, ds, acc[c].z);
            acc[c].w = fmaf(v.w, ds, acc[c].w);
        }
    }

    const float dd = dinv[node];
    const float dd2 = dd * dd;
    const float4* hs = reinterpret_cast<const float4*>(H + (size_t)node * F);
    const float4* bp = reinterpret_cast<const float4*>(bias);
    float4* ap = reinterpret_cast<float4*>(A + (size_t)node * F);
    #pragma unroll
    for (int c = 0; c < F4PL; ++c) {
        const int ci = lane + c * LPN;
        const float4 sv = hs[ci];
        const float4 bv = bp[ci];
        float4 r;
        r.x = fmaf(acc[c].x, dd, fmaf(sv.x, dd2, bv.x));
        r.y = fmaf(acc[c].y, dd, fmaf(sv.y, dd2, bv.y));
        r.z = fmaf(acc[c].z, dd, fmaf(sv.z, dd2, bv.z));
        r.w = fmaf(acc[c].w, dd, fmaf(sv.w, dd2, bv.w));
        ap[ci] = r;
    }
}

// ---------------- epilogue ----------------
__global__ void zero_one(float* p) { *p = 0.f; }

__global__ void relu_sum(float* __restrict__ Z, float* __restrict__ S, int total) {
    const size_t stride = (size_t)gridDim.x * blockDim.x;
    float local = 0.f;
    for (size_t idx = (size_t)blockIdx.x * blockDim.x + threadIdx.x;
         idx < (size_t)total; idx += stride) {
        float z = Z[idx];
        z = fmaxf(z, 0.f);
        Z[idx] = z;
        local += z;
    }
    #pragma unroll
    for (int off = 32; off; off >>= 1) local += __shfl_down(local, off);
    if ((threadIdx.x & 63) == 0) atomicAdd(S, local);
}

__global__ void final_norm(float* __restrict__ Z, const float* __restrict__ S, int N) {
    const int wid = threadIdx.x >> 6;
    const int lane = threadIdx.x & 63;
    const int row = blockIdx.x * 4 + wid;
    if (row >= N) return;
    const float inv = 1.0f / (*S);
    float v0 = Z[(size_t)row * 128 + lane] * inv;
    float v1 = Z[(size_t)row * 128 + lane + 64] * inv;
    const float t0 = tanhf(v0), t1 = tanhf(v1);
    const float y0 = t0 * t0, y1 = t1 * t1;
    float ss = y0 * y0 + y1 * y1;
    #pragma unroll
    for (int off = 32; off; off >>= 1) ss += __shfl_xor(ss, off);
    const float nrm = fmaxf(sqrtf(ss), 1e-12f);
    const float innrm = 1.0f / nrm;
    Z[(size_t)row * 128 + lane]      = y0 * innrm;
    Z[(size_t)row * 128 + lane + 64] = y1 * innrm;
}

extern "C" void kernel_launch(void* const* d_in, const int* in_sizes, int n_in,
                              void* d_out, int out_size, void* d_ws, size_t ws_size,
                              hipStream_t stream) {
    const float* x  = (const float*)d_in[0];
    const int*   ei = (const int*)d_in[1];
    const float* W1 = (const float*)d_in[2];
    const float* b1 = (const float*)d_in[3];
    const float* W2 = (const float*)d_in[4];
    const float* b2 = (const float*)d_in[5];
    const float* W3 = (const float*)d_in[6];
    const float* b3 = (const float*)d_in[7];
    float* out = (float*)d_out;

    const int N = NN, E = NE;
    const int* src = ei;
    const int* dst = ei + E;

    char* ws = (char*)d_ws;
    float* Hbuf = (float*)ws;                                  // N*512 f32
    float* Abuf = (float*)(ws + (size_t)N * 512 * 4);          // N*512 f32
    char* aux = ws + 2 * (size_t)N * 512 * 4;
    float* dinv   = (float*)(aux);
    int*   deg    = (int*)  (aux + 262144);
    int*   rowptr = (int*)  (aux + 524288);   // N+1 ints
    int*   cursor = (int*)  (aux + 786432);
    float* Ssum   = (float*)(aux + 1048576);
    int*   csr    = (int*)  (aux + 1310720);  // E ints

    // ---- CSR build + dinv ----
    zero_int<<<(N + 255) / 256, 256, 0, stream>>>(deg, N);
    edge_hist<<<(E + 255) / 256, 256, 0, stream>>>(dst, deg, E);
    make_dinv<<<(N + 255) / 256, 256, 0, stream>>>(deg, dinv, N);
    scan_deg<<<1, 1024, 0, stream>>>(deg, rowptr, cursor, N);
    build_csr<<<(E + 255) / 256, 256, 0, stream>>>(src, dst, cursor, csr, E);

    // ---- layer 1: x[Nx512] @ W1[512x512] -> H1(Hbuf); aggregate -> A1(Abuf) ----
    {
        dim3 g((N + 63) / 64, 512 / 64);
        gemm_k<0><<<g, 256, 0, stream>>>(x, W1, Hbuf, N, 512, 512);
        aggregate<512, 64><<<(N * 64 + 255) / 256, 256, 0, stream>>>(
            Hbuf, rowptr, csr, dinv, b1, Abuf, N);
    }
    // ---- layer 2: relu(A1)[Nx512] @ W2[512x256] -> H2; aggregate -> A2 ----
    float* H2 = Hbuf;
    float* A2 = Hbuf + (size_t)N * 256;
    {
        dim3 g((N + 63) / 64, 256 / 64);
        gemm_k<1><<<g, 256, 0, stream>>>(Abuf, W2, H2, N, 512, 256);
        aggregate<256, 64><<<(N * 64 + 255) / 256, 256, 0, stream>>>(
            H2, rowptr, csr, dinv, b2, A2, N);
    }
    // ---- layer 3: relu(A2)[Nx256] @ W3[256x128] -> H3(Abuf); aggregate -> d_out ----
    {
        dim3 g((N + 63) / 64, 128 / 64);
        gemm_k<1><<<g, 256, 0, stream>>>(A2, W3, Abuf, N, 256, 128);
        aggregate<128, 32><<<(N * 32 + 255) / 256, 256, 0, stream>>>(
            Abuf, rowptr, csr, dinv, b3, out, N);
    }
    // ---- epilogue ----
    zero_one<<<1, 1, 0, stream>>>(Ssum);
    relu_sum<<<2048, 256, 0, stream>>>(out, Ssum, N * 128);
    final_norm<<<(N + 3) / 4, 256, 0, stream>>>(out, Ssum, N);
}

// Round 3
// 565.664 us; speedup vs baseline: 9.5780x; 1.9808x over previous
//
#include <hip/hip_runtime.h>
#include <math.h>

#define NN 50000
#define NE 400000

typedef unsigned short u16;
typedef __bf16 bf16x8 __attribute__((ext_vector_type(8)));
typedef float f32x4 __attribute__((ext_vector_type(4)));
typedef u16 bfu8 __attribute__((ext_vector_type(8)));
typedef u16 bfu4 __attribute__((ext_vector_type(4)));

__device__ __forceinline__ u16 f2bf(float f) {
    unsigned u = __builtin_bit_cast(unsigned, f);
    u += 0x7fff + ((u >> 16) & 1);
    return (u16)(u >> 16);
}
__device__ __forceinline__ float bf2f(u16 h) {
    unsigned u = ((unsigned)h) << 16;
    return __builtin_bit_cast(float, u);
}

__device__ __forceinline__ void gload_lds16(const void* g, void* l) {
    typedef __attribute__((address_space(1))) const unsigned int GU;
    typedef __attribute__((address_space(3))) unsigned int LU;
    __builtin_amdgcn_global_load_lds((GU*)g, (LU*)l, 16, 0, 0);
}

// ---------------- conversions ----------------
__global__ void cvt_f32_bf16(const float* __restrict__ in, u16* __restrict__ out, int total4) {
    int i = blockIdx.x * blockDim.x + threadIdx.x;
    if (i >= total4) return;
    float4 v = reinterpret_cast<const float4*>(in)[i];
    bfu4 o;
    o[0] = f2bf(v.x); o[1] = f2bf(v.y); o[2] = f2bf(v.z); o[3] = f2bf(v.w);
    reinterpret_cast<bfu4*>(out)[i] = o;
}

// Wt[n][k] = bf16(W[k][n])
__global__ void transpose_w(const float* __restrict__ W, u16* __restrict__ Wt, int K, int NO) {
    int idx = blockIdx.x * blockDim.x + threadIdx.x;
    if (idx >= K * NO) return;
    int n = idx / K, k = idx - n * K;
    Wt[idx] = f2bf(W[(size_t)k * NO + n]);
}

// ---------------- degree / CSR ----------------
__global__ void zero_int(int* p, int n) {
    int i = blockIdx.x * blockDim.x + threadIdx.x;
    if (i < n) p[i] = 0;
}
__global__ void edge_hist(const int* __restrict__ dst, int* __restrict__ deg, int E) {
    int e = blockIdx.x * blockDim.x + threadIdx.x;
    if (e < E) atomicAdd(&deg[dst[e]], 1);
}
__global__ void make_dinv(const int* __restrict__ deg, float* __restrict__ dinv, int n) {
    int i = blockIdx.x * blockDim.x + threadIdx.x;
    if (i < n) dinv[i] = rsqrtf(1.0f + (float)deg[i]);
}
__global__ __launch_bounds__(1024) void scan_deg(const int* __restrict__ deg,
                                                 int* __restrict__ rowptr,
                                                 int* __restrict__ cursor, int N) {
    __shared__ int sd[1024];
    __shared__ int carry;
    if (threadIdx.x == 0) carry = 0;
    __syncthreads();
    for (int base = 0; base < N; base += 1024) {
        const int i = base + threadIdx.x;
        const int v = (i < N) ? deg[i] : 0;
        sd[threadIdx.x] = v;
        __syncthreads();
        for (int off = 1; off < 1024; off <<= 1) {
            int t = (threadIdx.x >= off) ? sd[threadIdx.x - off] : 0;
            __syncthreads();
            sd[threadIdx.x] += t;
            __syncthreads();
        }
        const int excl = carry + sd[threadIdx.x] - v;
        if (i < N) { rowptr[i] = excl; cursor[i] = excl; }
        __syncthreads();
        if (threadIdx.x == 1023) carry += sd[1023];
        __syncthreads();
    }
    if (threadIdx.x == 0) rowptr[N] = carry;
}
__global__ void build_csr(const int* __restrict__ src, const int* __restrict__ dst,
                          int* __restrict__ cursor, int* __restrict__ csr_src, int E) {
    int e = blockIdx.x * blockDim.x + threadIdx.x;
    if (e < E) {
        int pos = atomicAdd(&cursor[dst[e]], 1);
        csr_src[pos] = src[e];
    }
}

// ---------------- bf16 MFMA GEMM: H = X @ Wt^T ----------------
// X [N][K] bf16, Wt [NO][K] bf16, H [N][NO] bf16. 128x128 tile, BK=32, 4 waves.
__global__ __launch_bounds__(256) void gemm_bf16(
    const u16* __restrict__ X, const u16* __restrict__ Wt,
    u16* __restrict__ H, int N, int K, int NO)
{
    __shared__ unsigned char lds[33792];
    const int tid = threadIdx.x;
    const int w = tid >> 6;
    const int lane = tid & 63;
    const int m0 = blockIdx.x * 128;
    const int n0 = blockIdx.y * 128;

    f32x4 acc[4][4] = {};

    // staging map: load i in {0,1}; linear lds half-slot idx = i*256+tid
    int arow[2], gcol[2];
    int agrow[2], bgrow[2];
    #pragma unroll
    for (int i = 0; i < 2; ++i) {
        int idx = i * 256 + tid;
        int r = idx >> 2;
        int s = (idx & 3) ^ (r & 3);   // XOR-swizzled source slot
        arow[i] = r;
        gcol[i] = s * 8;
        int ag = m0 + r; if (ag >= N) ag = N - 1;
        agrow[i] = ag;
        bgrow[i] = n0 + r;
    }

    for (int k0 = 0; k0 < K; k0 += 32) {
        #pragma unroll
        for (int i = 0; i < 2; ++i) {
            gload_lds16(X + (size_t)agrow[i] * K + k0 + gcol[i],
                        lds + i * 4096 + w * 1024);
            gload_lds16(Wt + (size_t)bgrow[i] * K + k0 + gcol[i],
                        lds + 8192 + i * 4096 + w * 1024);
        }
        asm volatile("s_waitcnt vmcnt(0)" ::: "memory");
        __syncthreads();

        bf16x8 af[4], bfr[4];
        #pragma unroll
        for (int m = 0; m < 4; ++m) {
            int r = (w >> 1) * 64 + m * 16 + (lane & 15);
            int off = r * 64 + (((lane >> 4) ^ (r & 3)) * 16);
            af[m] = *reinterpret_cast<const bf16x8*>(lds + off);
        }
        #pragma unroll
        for (int n = 0; n < 4; ++n) {
            int r = (w & 1) * 64 + n * 16 + (lane & 15);
            int off = 8192 + r * 64 + (((lane >> 4) ^ (r & 3)) * 16);
            bfr[n] = *reinterpret_cast<const bf16x8*>(lds + off);
        }
        #pragma unroll
        for (int m = 0; m < 4; ++m)
            #pragma unroll
            for (int n = 0; n < 4; ++n)
                acc[m][n] = __builtin_amdgcn_mfma_f32_16x16x32_bf16(
                    af[m], bfr[n], acc[m][n], 0, 0, 0);
        __syncthreads();
    }

    // epilogue: repack through LDS, 2 chunks of 64 cols, coalesced bf16 stores
    float* Cs = reinterpret_cast<float*>(lds);
    #pragma unroll
    for (int c = 0; c < 2; ++c) {
        __syncthreads();
        if ((w & 1) == c) {
            const int rbase = (w >> 1) * 64;
            #pragma unroll
            for (int m = 0; m < 4; ++m)
                #pragma unroll
                for (int n = 0; n < 4; ++n)
                    #pragma unroll
                    for (int r = 0; r < 4; ++r) {
                        int row = rbase + m * 16 + (lane >> 4) * 4 + r;
                        int col = n * 16 + (lane & 15);
                        Cs[row * 66 + col] = acc[m][n][r];
                    }
        }
        __syncthreads();
        const int row = tid >> 1;
        const int half = tid & 1;
        const int grow = m0 + row;
        if (grow < N) {
            const float* p = Cs + row * 66 + half * 32;
            bfu8 o0, o1, o2, o3;
            #pragma unroll
            for (int j = 0; j < 8; ++j) o0[j] = f2bf(p[j]);
            #pragma unroll
            for (int j = 0; j < 8; ++j) o1[j] = f2bf(p[8 + j]);
            #pragma unroll
            for (int j = 0; j < 8; ++j) o2[j] = f2bf(p[16 + j]);
            #pragma unroll
            for (int j = 0; j < 8; ++j) o3[j] = f2bf(p[24 + j]);
            bfu8* dst = reinterpret_cast<bfu8*>(H + (size_t)grow * NO + n0 + c * 64 + half * 32);
            dst[0] = o0; dst[1] = o1; dst[2] = o2; dst[3] = o3;
        }
    }
}

// ---------------- CSR pull-aggregate (bf16 H) ----------------
// r = dinv[d]*sum(dinv[s]*H[s]) + dinv[d]^2*H[d] + bias ; optional relu+bf16 out
template <int F, int LPN, bool BFOUT>
__global__ __launch_bounds__(256) void aggregate_bf(
    const u16* __restrict__ H, const int* __restrict__ rowptr,
    const int* __restrict__ csr_src, const float* __restrict__ dinv,
    const float* __restrict__ bias, void* __restrict__ Aout, int N)
{
    constexpr int EPL = F / LPN;   // elems per lane
    const int gtid = blockIdx.x * blockDim.x + threadIdx.x;
    const int node = gtid / LPN;
    const int lane = gtid - node * LPN;
    if (node >= N) return;
    const int co = lane * EPL;

    float acc[EPL];
    #pragma unroll
    for (int q = 0; q < EPL; ++q) acc[q] = 0.f;

    const int beg = rowptr[node], end = rowptr[node + 1];
    for (int j = beg; j < end; ++j) {
        const int s = csr_src[j];
        const float ds = dinv[s];
        if constexpr (EPL == 8) {
            bfu8 v = *reinterpret_cast<const bfu8*>(H + (size_t)s * F + co);
            #pragma unroll
            for (int q = 0; q < 8; ++q) acc[q] = fmaf(bf2f(v[q]), ds, acc[q]);
        } else {
            bfu4 v = *reinterpret_cast<const bfu4*>(H + (size_t)s * F + co);
            #pragma unroll
            for (int q = 0; q < EPL; ++q) acc[q] = fmaf(bf2f(v[q]), ds, acc[q]);
        }
    }

    const float dd = dinv[node], dd2 = dd * dd;
    float r[EPL];
    if constexpr (EPL == 8) {
        bfu8 sv = *reinterpret_cast<const bfu8*>(H + (size_t)node * F + co);
        #pragma unroll
        for (int q = 0; q < 8; ++q)
            r[q] = fmaf(acc[q], dd, fmaf(bf2f(sv[q]), dd2, bias[co + q]));
    } else {
        bfu4 sv = *reinterpret_cast<const bfu4*>(H + (size_t)node * F + co);
        #pragma unroll
        for (int q = 0; q < EPL; ++q)
            r[q] = fmaf(acc[q], dd, fmaf(bf2f(sv[q]), dd2, bias[co + q]));
    }

    if constexpr (BFOUT) {
        u16* out = reinterpret_cast<u16*>(Aout) + (size_t)node * F + co;
        if constexpr (EPL == 8) {
            bfu8 o;
            #pragma unroll
            for (int q = 0; q < 8; ++q) o[q] = f2bf(fmaxf(r[q], 0.f));
            *reinterpret_cast<bfu8*>(out) = o;
        } else {
            bfu4 o;
            #pragma unroll
            for (int q = 0; q < EPL; ++q) o[q] = f2bf(fmaxf(r[q], 0.f));
            *reinterpret_cast<bfu4*>(out) = o;
        }
    } else {
        float* out = reinterpret_cast<float*>(Aout) + (size_t)node * F + co;
        #pragma unroll
        for (int q = 0; q < EPL; ++q) out[q] = r[q];
    }
}

// ---------------- epilogue ----------------
__global__ void zero_one(float* p) { *p = 0.f; }

__global__ void relu_sum(float* __restrict__ Z, float* __restrict__ S, int total) {
    const size_t stride = (size_t)gridDim.x * blockDim.x;
    float local = 0.f;
    for (size_t idx = (size_t)blockIdx.x * blockDim.x + threadIdx.x;
         idx < (size_t)total; idx += stride) {
        float z = Z[idx];
        z = fmaxf(z, 0.f);
        Z[idx] = z;
        local += z;
    }
    #pragma unroll
    for (int off = 32; off; off >>= 1) local += __shfl_down(local, off);
    if ((threadIdx.x & 63) == 0) atomicAdd(S, local);
}

__global__ void final_norm(float* __restrict__ Z, const float* __restrict__ S, int N) {
    const int wid = threadIdx.x >> 6;
    const int lane = threadIdx.x & 63;
    const int row = blockIdx.x * 4 + wid;
    if (row >= N) return;
    const float inv = 1.0f / (*S);
    float v0 = Z[(size_t)row * 128 + lane] * inv;
    float v1 = Z[(size_t)row * 128 + lane + 64] * inv;
    const float t0 = tanhf(v0), t1 = tanhf(v1);
    const float y0 = t0 * t0, y1 = t1 * t1;
    float ss = y0 * y0 + y1 * y1;
    #pragma unroll
    for (int off = 32; off; off >>= 1) ss += __shfl_xor(ss, off);
    const float nrm = fmaxf(sqrtf(ss), 1e-12f);
    const float innrm = 1.0f / nrm;
    Z[(size_t)row * 128 + lane]      = y0 * innrm;
    Z[(size_t)row * 128 + lane + 64] = y1 * innrm;
}

extern "C" void kernel_launch(void* const* d_in, const int* in_sizes, int n_in,
                              void* d_out, int out_size, void* d_ws, size_t ws_size,
                              hipStream_t stream) {
    const float* x  = (const float*)d_in[0];
    const int*   ei = (const int*)d_in[1];
    const float* W1 = (const float*)d_in[2];
    const float* b1 = (const float*)d_in[3];
    const float* W2 = (const float*)d_in[4];
    const float* b2 = (const float*)d_in[5];
    const float* W3 = (const float*)d_in[6];
    const float* b3 = (const float*)d_in[7];
    float* out = (float*)d_out;

    const int N = NN, E = NE;
    const int* src = ei;
    const int* dst = ei + E;

    char* ws = (char*)d_ws;
    size_t off = 0;
    u16* bufA = (u16*)(ws + off); off += (size_t)N * 512 * 2;   // 51.2 MB
    u16* bufB = (u16*)(ws + off); off += (size_t)N * 512 * 2;   // 51.2 MB
    u16* Wt1 = (u16*)(ws + off); off += 512 * 512 * 2;
    u16* Wt2 = (u16*)(ws + off); off += 256 * 512 * 2;
    u16* Wt3 = (u16*)(ws + off); off += 128 * 256 * 2;
    float* dinv   = (float*)(ws + off); off += 204800;
    int*   deg    = (int*)  (ws + off); off += 204800;
    int*   rowptr = (int*)  (ws + off); off += 204800;
    int*   cursor = (int*)  (ws + off); off += 204800;
    float* Ssum   = (float*)(ws + off); off += 256;
    int*   csr    = (int*)  (ws + off); off += (size_t)E * 4;

    // ---- conversions ----
    cvt_f32_bf16<<<(N * 512 / 4 + 255) / 256, 256, 0, stream>>>(x, bufA, N * 512 / 4);
    transpose_w<<<(512 * 512 + 255) / 256, 256, 0, stream>>>(W1, Wt1, 512, 512);
    transpose_w<<<(512 * 256 + 255) / 256, 256, 0, stream>>>(W2, Wt2, 512, 256);
    transpose_w<<<(256 * 128 + 255) / 256, 256, 0, stream>>>(W3, Wt3, 256, 128);

    // ---- CSR + dinv ----
    zero_int<<<(N + 255) / 256, 256, 0, stream>>>(deg, N);
    edge_hist<<<(E + 255) / 256, 256, 0, stream>>>(dst, deg, E);
    make_dinv<<<(N + 255) / 256, 256, 0, stream>>>(deg, dinv, N);
    scan_deg<<<1, 1024, 0, stream>>>(deg, rowptr, cursor, N);
    build_csr<<<(E + 255) / 256, 256, 0, stream>>>(src, dst, cursor, csr, E);

    const int MT = (N + 127) / 128;
    // ---- layer 1 ----
    gemm_bf16<<<dim3(MT, 4), 256, 0, stream>>>(bufA, Wt1, bufB, N, 512, 512);
    aggregate_bf<512, 64, true><<<(N * 64 + 255) / 256, 256, 0, stream>>>(
        bufB, rowptr, csr, dinv, b1, bufA, N);
    // ---- layer 2 ----
    gemm_bf16<<<dim3(MT, 2), 256, 0, stream>>>(bufA, Wt2, bufB, N, 512, 256);
    aggregate_bf<256, 64, true><<<(N * 64 + 255) / 256, 256, 0, stream>>>(
        bufB, rowptr, csr, dinv, b2, bufA, N);
    // ---- layer 3 ----
    gemm_bf16<<<dim3(MT, 1), 256, 0, stream>>>(bufA, Wt3, bufB, N, 256, 128);
    aggregate_bf<128, 32, false><<<(N * 32 + 255) / 256, 256, 0, stream>>>(
        bufB, rowptr, csr, dinv, b3, out, N);

    // ---- epilogue ----
    zero_one<<<1, 1, 0, stream>>>(Ssum);
    relu_sum<<<2048, 256, 0, stream>>>(out, Ssum, N * 128);
    final_norm<<<(N + 3) / 4, 256, 0, stream>>>(out, Ssum, N);
}

// Round 4
// 472.074 us; speedup vs baseline: 11.4769x; 1.1983x over previous
//
#include <hip/hip_runtime.h>
#include <math.h>

#define NN 50000
#define NE 400000

typedef unsigned short u16;
typedef __bf16 bf16x8 __attribute__((ext_vector_type(8)));
typedef float f32x4 __attribute__((ext_vector_type(4)));
typedef u16 bfu8 __attribute__((ext_vector_type(8)));
typedef u16 bfu4 __attribute__((ext_vector_type(4)));

__device__ __forceinline__ u16 f2bf(float f) {
    unsigned u = __builtin_bit_cast(unsigned, f);
    u += 0x7fff + ((u >> 16) & 1);
    return (u16)(u >> 16);
}
__device__ __forceinline__ float bf2f(u16 h) {
    unsigned u = ((unsigned)h) << 16;
    return __builtin_bit_cast(float, u);
}

__device__ __forceinline__ void gload_lds16(const void* g, void* l) {
    typedef __attribute__((address_space(1))) const unsigned int GU;
    typedef __attribute__((address_space(3))) unsigned int LU;
    __builtin_amdgcn_global_load_lds((GU*)g, (LU*)l, 16, 0, 0);
}

// ---------------- conversions ----------------
__global__ void cvt_f32_bf16(const float* __restrict__ in, u16* __restrict__ out, int total4) {
    int i = blockIdx.x * blockDim.x + threadIdx.x;
    if (i >= total4) return;
    float4 v = reinterpret_cast<const float4*>(in)[i];
    bfu4 o;
    o[0] = f2bf(v.x); o[1] = f2bf(v.y); o[2] = f2bf(v.z); o[3] = f2bf(v.w);
    reinterpret_cast<bfu4*>(out)[i] = o;
}

// Wt[n][k] = bf16(W[k][n])
__global__ void transpose_w(const float* __restrict__ W, u16* __restrict__ Wt, int K, int NO) {
    int idx = blockIdx.x * blockDim.x + threadIdx.x;
    if (idx >= K * NO) return;
    int n = idx / K, k = idx - n * K;
    Wt[idx] = f2bf(W[(size_t)k * NO + n]);
}

// ---------------- degree / CSR ----------------
__global__ void zero_int(int* p, int n) {
    int i = blockIdx.x * blockDim.x + threadIdx.x;
    if (i < n) p[i] = 0;
}
__global__ void edge_hist(const int* __restrict__ dst, int* __restrict__ deg, int E) {
    int e = blockIdx.x * blockDim.x + threadIdx.x;
    if (e < E) atomicAdd(&deg[dst[e]], 1);
}
__global__ void make_dinv(const int* __restrict__ deg, float* __restrict__ dinv, int n) {
    int i = blockIdx.x * blockDim.x + threadIdx.x;
    if (i < n) dinv[i] = rsqrtf(1.0f + (float)deg[i]);
}

// one-pass chunked scan: 1024 threads, thread t owns CHUNK contiguous nodes
__global__ __launch_bounds__(1024) void scan_deg(const int* __restrict__ deg,
                                                 int* __restrict__ rowptr,
                                                 int* __restrict__ cursor, int N) {
    const int CHUNK = (N + 1023) / 1024;
    const int t = threadIdx.x;
    const int lane = t & 63, wid = t >> 6;
    const int i0 = t * CHUNK;
    const int i1 = min(i0 + CHUNK, N);

    int lsum = 0;
    for (int i = i0; i < i1; ++i) lsum += deg[i];

    int inc = lsum;
    #pragma unroll
    for (int off = 1; off < 64; off <<= 1) {
        int v = __shfl_up(inc, off);
        if (lane >= off) inc += v;
    }
    __shared__ int wsums[16];
    if (lane == 63) wsums[wid] = inc;
    __syncthreads();
    int woff = 0;
    for (int w2 = 0; w2 < wid; ++w2) woff += wsums[w2];
    int p = woff + inc - lsum;   // exclusive prefix of this thread's chunk

    for (int i = i0; i < i1; ++i) {
        rowptr[i] = p; cursor[i] = p;
        p += deg[i];
    }
    if (t == 1023) rowptr[N] = woff + inc;
}

__global__ void build_csr(const int* __restrict__ src, const int* __restrict__ dst,
                          int* __restrict__ cursor, int* __restrict__ csr_src, int E) {
    int e = blockIdx.x * blockDim.x + threadIdx.x;
    if (e < E) {
        int pos = atomicAdd(&cursor[dst[e]], 1);
        csr_src[pos] = src[e];
    }
}

// ---------------- bf16 MFMA GEMM: H = X @ Wt^T ----------------
__global__ __launch_bounds__(256) void gemm_bf16(
    const u16* __restrict__ X, const u16* __restrict__ Wt,
    u16* __restrict__ H, int N, int K, int NO)
{
    __shared__ unsigned char lds[33792];
    const int tid = threadIdx.x;
    const int w = tid >> 6;
    const int lane = tid & 63;
    const int m0 = blockIdx.x * 128;
    const int n0 = blockIdx.y * 128;

    f32x4 acc[4][4] = {};

    int gcol[2];
    int agrow[2], bgrow[2];
    #pragma unroll
    for (int i = 0; i < 2; ++i) {
        int idx = i * 256 + tid;
        int r = idx >> 2;
        int s = (idx & 3) ^ (r & 3);
        gcol[i] = s * 8;
        int ag = m0 + r; if (ag >= N) ag = N - 1;
        agrow[i] = ag;
        bgrow[i] = n0 + r;
    }

    for (int k0 = 0; k0 < K; k0 += 32) {
        #pragma unroll
        for (int i = 0; i < 2; ++i) {
            gload_lds16(X + (size_t)agrow[i] * K + k0 + gcol[i],
                        lds + i * 4096 + w * 1024);
            gload_lds16(Wt + (size_t)bgrow[i] * K + k0 + gcol[i],
                        lds + 8192 + i * 4096 + w * 1024);
        }
        asm volatile("s_waitcnt vmcnt(0)" ::: "memory");
        __syncthreads();

        bf16x8 af[4], bfr[4];
        #pragma unroll
        for (int m = 0; m < 4; ++m) {
            int r = (w >> 1) * 64 + m * 16 + (lane & 15);
            int off = r * 64 + (((lane >> 4) ^ (r & 3)) * 16);
            af[m] = *reinterpret_cast<const bf16x8*>(lds + off);
        }
        #pragma unroll
        for (int n = 0; n < 4; ++n) {
            int r = (w & 1) * 64 + n * 16 + (lane & 15);
            int off = 8192 + r * 64 + (((lane >> 4) ^ (r & 3)) * 16);
            bfr[n] = *reinterpret_cast<const bf16x8*>(lds + off);
        }
        #pragma unroll
        for (int m = 0; m < 4; ++m)
            #pragma unroll
            for (int n = 0; n < 4; ++n)
                acc[m][n] = __builtin_amdgcn_mfma_f32_16x16x32_bf16(
                    af[m], bfr[n], acc[m][n], 0, 0, 0);
        __syncthreads();
    }

    float* Cs = reinterpret_cast<float*>(lds);
    #pragma unroll
    for (int c = 0; c < 2; ++c) {
        __syncthreads();
        if ((w & 1) == c) {
            const int rbase = (w >> 1) * 64;
            #pragma unroll
            for (int m = 0; m < 4; ++m)
                #pragma unroll
                for (int n = 0; n < 4; ++n)
                    #pragma unroll
                    for (int r = 0; r < 4; ++r) {
                        int row = rbase + m * 16 + (lane >> 4) * 4 + r;
                        int col = n * 16 + (lane & 15);
                        Cs[row * 66 + col] = acc[m][n][r];
                    }
        }
        __syncthreads();
        const int row = tid >> 1;
        const int half = tid & 1;
        const int grow = m0 + row;
        if (grow < N) {
            const float* p = Cs + row * 66 + half * 32;
            bfu8 o0, o1, o2, o3;
            #pragma unroll
            for (int j = 0; j < 8; ++j) o0[j] = f2bf(p[j]);
            #pragma unroll
            for (int j = 0; j < 8; ++j) o1[j] = f2bf(p[8 + j]);
            #pragma unroll
            for (int j = 0; j < 8; ++j) o2[j] = f2bf(p[16 + j]);
            #pragma unroll
            for (int j = 0; j < 8; ++j) o3[j] = f2bf(p[24 + j]);
            bfu8* dst = reinterpret_cast<bfu8*>(H + (size_t)grow * NO + n0 + c * 64 + half * 32);
            dst[0] = o0; dst[1] = o1; dst[2] = o2; dst[3] = o3;
        }
    }
}

// ---------------- CSR pull-aggregate (bf16 H) ----------------
// r = dinv[d]*sum(dinv[s]*H[s]) + dinv[d]^2*H[d] + bias
// BFOUT: relu+bf16 out. SUMOUT: relu+f32 out + per-block partial sum.
template <int F, int LPN, bool BFOUT, bool SUMOUT>
__global__ __launch_bounds__(256) void aggregate_bf(
    const u16* __restrict__ H, const int* __restrict__ rowptr,
    const int* __restrict__ csr_src, const float* __restrict__ dinv,
    const float* __restrict__ bias, void* __restrict__ Aout,
    float* __restrict__ partials, int N)
{
    constexpr int EPL = F / LPN;
    const int gtid = blockIdx.x * blockDim.x + threadIdx.x;
    const int node = gtid / LPN;
    const int lane = gtid - node * LPN;
    const int co = lane * EPL;
    const bool valid = node < N;

    float acc[EPL];
    #pragma unroll
    for (int q = 0; q < EPL; ++q) acc[q] = 0.f;

    if (valid) {
        const int beg = rowptr[node], end = rowptr[node + 1];
        for (int j = beg; j < end; ++j) {
            const int s = csr_src[j];
            const float ds = dinv[s];
            if constexpr (EPL == 8) {
                bfu8 v = *reinterpret_cast<const bfu8*>(H + (size_t)s * F + co);
                #pragma unroll
                for (int q = 0; q < 8; ++q) acc[q] = fmaf(bf2f(v[q]), ds, acc[q]);
            } else {
                bfu4 v = *reinterpret_cast<const bfu4*>(H + (size_t)s * F + co);
                #pragma unroll
                for (int q = 0; q < EPL; ++q) acc[q] = fmaf(bf2f(v[q]), ds, acc[q]);
            }
        }
    }

    float r[EPL];
    #pragma unroll
    for (int q = 0; q < EPL; ++q) r[q] = 0.f;
    if (valid) {
        const float dd = dinv[node], dd2 = dd * dd;
        if constexpr (EPL == 8) {
            bfu8 sv = *reinterpret_cast<const bfu8*>(H + (size_t)node * F + co);
            #pragma unroll
            for (int q = 0; q < 8; ++q)
                r[q] = fmaf(acc[q], dd, fmaf(bf2f(sv[q]), dd2, bias[co + q]));
        } else {
            bfu4 sv = *reinterpret_cast<const bfu4*>(H + (size_t)node * F + co);
            #pragma unroll
            for (int q = 0; q < EPL; ++q)
                r[q] = fmaf(acc[q], dd, fmaf(bf2f(sv[q]), dd2, bias[co + q]));
        }
    }

    if constexpr (BFOUT) {
        if (valid) {
            u16* out = reinterpret_cast<u16*>(Aout) + (size_t)node * F + co;
            if constexpr (EPL == 8) {
                bfu8 o;
                #pragma unroll
                for (int q = 0; q < 8; ++q) o[q] = f2bf(fmaxf(r[q], 0.f));
                *reinterpret_cast<bfu8*>(out) = o;
            } else {
                bfu4 o;
                #pragma unroll
                for (int q = 0; q < EPL; ++q) o[q] = f2bf(fmaxf(r[q], 0.f));
                *reinterpret_cast<bfu4*>(out) = o;
            }
        }
    } else if constexpr (SUMOUT) {
        float ls = 0.f;
        if (valid) {
            float* out = reinterpret_cast<float*>(Aout) + (size_t)node * F + co;
            #pragma unroll
            for (int q = 0; q < EPL; ++q) {
                const float z = fmaxf(r[q], 0.f);
                out[q] = z;
                ls += z;
            }
        }
        // block reduce -> partials[blockIdx.x]
        const int wl = threadIdx.x & 63, wi = threadIdx.x >> 6;
        #pragma unroll
        for (int off = 32; off; off >>= 1) ls += __shfl_down(ls, off);
        __shared__ float wsum[4];
        if (wl == 0) wsum[wi] = ls;
        __syncthreads();
        if (threadIdx.x == 0)
            partials[blockIdx.x] = wsum[0] + wsum[1] + wsum[2] + wsum[3];
    } else {
        if (valid) {
            float* out = reinterpret_cast<float*>(Aout) + (size_t)node * F + co;
            #pragma unroll
            for (int q = 0; q < EPL; ++q) out[q] = r[q];
        }
    }
}

// ---------------- epilogue ----------------
__global__ __launch_bounds__(1024) void reduce_partials(const float* __restrict__ partials,
                                                        float* __restrict__ S, int n) {
    float local = 0.f;
    for (int i = threadIdx.x; i < n; i += 1024) local += partials[i];
    const int lane = threadIdx.x & 63, wid = threadIdx.x >> 6;
    #pragma unroll
    for (int off = 32; off; off >>= 1) local += __shfl_down(local, off);
    __shared__ float wsum[16];
    if (lane == 0) wsum[wid] = local;
    __syncthreads();
    if (threadIdx.x == 0) {
        float t = 0.f;
        #pragma unroll
        for (int i = 0; i < 16; ++i) t += wsum[i];
        *S = t;
    }
}

__global__ void final_norm(float* __restrict__ Z, const float* __restrict__ S, int N) {
    const int wid = threadIdx.x >> 6;
    const int lane = threadIdx.x & 63;
    const int row = blockIdx.x * 4 + wid;
    if (row >= N) return;
    const float inv = 1.0f / (*S);
    float v0 = Z[(size_t)row * 128 + lane] * inv;
    float v1 = Z[(size_t)row * 128 + lane + 64] * inv;
    const float t0 = tanhf(v0), t1 = tanhf(v1);
    const float y0 = t0 * t0, y1 = t1 * t1;
    float ss = y0 * y0 + y1 * y1;
    #pragma unroll
    for (int off = 32; off; off >>= 1) ss += __shfl_xor(ss, off);
    const float nrm = fmaxf(sqrtf(ss), 1e-12f);
    const float innrm = 1.0f / nrm;
    Z[(size_t)row * 128 + lane]      = y0 * innrm;
    Z[(size_t)row * 128 + lane + 64] = y1 * innrm;
}

extern "C" void kernel_launch(void* const* d_in, const int* in_sizes, int n_in,
                              void* d_out, int out_size, void* d_ws, size_t ws_size,
                              hipStream_t stream) {
    const float* x  = (const float*)d_in[0];
    const int*   ei = (const int*)d_in[1];
    const float* W1 = (const float*)d_in[2];
    const float* b1 = (const float*)d_in[3];
    const float* W2 = (const float*)d_in[4];
    const float* b2 = (const float*)d_in[5];
    const float* W3 = (const float*)d_in[6];
    const float* b3 = (const float*)d_in[7];
    float* out = (float*)d_out;

    const int N = NN, E = NE;
    const int* src = ei;
    const int* dst = ei + E;

    char* ws = (char*)d_ws;
    size_t off = 0;
    u16* bufA = (u16*)(ws + off); off += (size_t)N * 512 * 2;
    u16* bufB = (u16*)(ws + off); off += (size_t)N * 512 * 2;
    u16* Wt1 = (u16*)(ws + off); off += 512 * 512 * 2;
    u16* Wt2 = (u16*)(ws + off); off += 256 * 512 * 2;
    u16* Wt3 = (u16*)(ws + off); off += 128 * 256 * 2;
    float* dinv   = (float*)(ws + off); off += 204800;
    int*   deg    = (int*)  (ws + off); off += 204800;
    int*   rowptr = (int*)  (ws + off); off += 204800;
    int*   cursor = (int*)  (ws + off); off += 204800;
    float* Ssum   = (float*)(ws + off); off += 256;
    float* partials = (float*)(ws + off); off += 32768;   // up to 8192 blocks
    int*   csr    = (int*)  (ws + off); off += (size_t)E * 4;

    // ---- conversions ----
    cvt_f32_bf16<<<(N * 512 / 4 + 255) / 256, 256, 0, stream>>>(x, bufA, N * 512 / 4);
    transpose_w<<<(512 * 512 + 255) / 256, 256, 0, stream>>>(W1, Wt1, 512, 512);
    transpose_w<<<(512 * 256 + 255) / 256, 256, 0, stream>>>(W2, Wt2, 512, 256);
    transpose_w<<<(256 * 128 + 255) / 256, 256, 0, stream>>>(W3, Wt3, 256, 128);

    // ---- CSR + dinv ----
    zero_int<<<(N + 255) / 256, 256, 0, stream>>>(deg, N);
    edge_hist<<<(E + 255) / 256, 256, 0, stream>>>(dst, deg, E);
    make_dinv<<<(N + 255) / 256, 256, 0, stream>>>(deg, dinv, N);
    scan_deg<<<1, 1024, 0, stream>>>(deg, rowptr, cursor, N);
    build_csr<<<(E + 255) / 256, 256, 0, stream>>>(src, dst, cursor, csr, E);

    const int MT = (N + 127) / 128;
    // ---- layer 1 ----
    gemm_bf16<<<dim3(MT, 4), 256, 0, stream>>>(bufA, Wt1, bufB, N, 512, 512);
    aggregate_bf<512, 64, true, false><<<(N * 64 + 255) / 256, 256, 0, stream>>>(
        bufB, rowptr, csr, dinv, b1, bufA, nullptr, N);
    // ---- layer 2 ----
    gemm_bf16<<<dim3(MT, 2), 256, 0, stream>>>(bufA, Wt2, bufB, N, 512, 256);
    aggregate_bf<256, 64, true, false><<<(N * 64 + 255) / 256, 256, 0, stream>>>(
        bufB, rowptr, csr, dinv, b2, bufA, nullptr, N);
    // ---- layer 3: aggregate fuses relu + partial sums ----
    gemm_bf16<<<dim3(MT, 1), 256, 0, stream>>>(bufA, Wt3, bufB, N, 256, 128);
    const int aggBlocks3 = (N * 32 + 255) / 256;
    aggregate_bf<128, 32, false, true><<<aggBlocks3, 256, 0, stream>>>(
        bufB, rowptr, csr, dinv, b3, out, partials, N);

    // ---- epilogue ----
    reduce_partials<<<1, 1024, 0, stream>>>(partials, Ssum, aggBlocks3);
    final_norm<<<(N + 3) / 4, 256, 0, stream>>>(out, Ssum, N);
}

// Round 5
// 370.537 us; speedup vs baseline: 14.6219x; 1.2740x over previous
//
#include <hip/hip_runtime.h>
#include <math.h>

#define NN 50000
#define NE 400000

typedef unsigned short u16;
typedef __bf16 bf16x8 __attribute__((ext_vector_type(8)));
typedef float f32x4 __attribute__((ext_vector_type(4)));
typedef u16 bfu8 __attribute__((ext_vector_type(8)));
typedef u16 bfu4 __attribute__((ext_vector_type(4)));

__device__ __forceinline__ u16 f2bf(float f) {
    unsigned u = __builtin_bit_cast(unsigned, f);
    u += 0x7fff + ((u >> 16) & 1);
    return (u16)(u >> 16);
}
__device__ __forceinline__ float bf2f(u16 h) {
    unsigned u = ((unsigned)h) << 16;
    return __builtin_bit_cast(float, u);
}

__device__ __forceinline__ void gload_lds16(const void* g, void* l) {
    typedef __attribute__((address_space(1))) const unsigned int GU;
    typedef __attribute__((address_space(3))) unsigned int LU;
    __builtin_amdgcn_global_load_lds((GU*)g, (LU*)l, 16, 0, 0);
}

// ---------------- conversions ----------------
__global__ void cvt_f32_bf16(const float* __restrict__ in, u16* __restrict__ out, int total4) {
    int i = blockIdx.x * blockDim.x + threadIdx.x;
    if (i >= total4) return;
    float4 v = reinterpret_cast<const float4*>(in)[i];
    bfu4 o;
    o[0] = f2bf(v.x); o[1] = f2bf(v.y); o[2] = f2bf(v.z); o[3] = f2bf(v.w);
    reinterpret_cast<bfu4*>(out)[i] = o;
}

// Wt[n][k] = bf16(W[k][n])
__global__ void transpose_w(const float* __restrict__ W, u16* __restrict__ Wt, int K, int NO) {
    int idx = blockIdx.x * blockDim.x + threadIdx.x;
    if (idx >= K * NO) return;
    int n = idx / K, k = idx - n * K;
    Wt[idx] = f2bf(W[(size_t)k * NO + n]);
}

// ---------------- degree / CSR ----------------
__global__ void zero_int(int* p, int n) {
    int i = blockIdx.x * blockDim.x + threadIdx.x;
    if (i < n) p[i] = 0;
}
__global__ void edge_hist(const int* __restrict__ dst, int* __restrict__ deg, int E) {
    int e = blockIdx.x * blockDim.x + threadIdx.x;
    if (e < E) atomicAdd(&deg[dst[e]], 1);
}

// Phase A: per-block sum of deg (256/node block) + fused dinv
__global__ __launch_bounds__(256) void deg_block_sum(const int* __restrict__ deg,
                                                     float* __restrict__ dinv,
                                                     int* __restrict__ bsum, int N) {
    const int i = blockIdx.x * 256 + threadIdx.x;
    int v = 0;
    if (i < N) { v = deg[i]; dinv[i] = rsqrtf(1.0f + (float)v); }
    int s = v;
    #pragma unroll
    for (int off = 32; off; off >>= 1) s += __shfl_down(s, off);
    __shared__ int ws[4];
    if ((threadIdx.x & 63) == 0) ws[threadIdx.x >> 6] = s;
    __syncthreads();
    if (threadIdx.x == 0) bsum[blockIdx.x] = ws[0] + ws[1] + ws[2] + ws[3];
}

// Phase B: exclusive scan of block sums (nb <= 256), writes rowptr[N]=total
__global__ __launch_bounds__(256) void scan_bsums(int* __restrict__ bsum,
                                                  int* __restrict__ rowptrN, int nb) {
    const int t = threadIdx.x;
    const int lane = t & 63, wid = t >> 6;
    int v = (t < nb) ? bsum[t] : 0;
    int inc = v;
    #pragma unroll
    for (int off = 1; off < 64; off <<= 1) {
        int u = __shfl_up(inc, off);
        if (lane >= off) inc += u;
    }
    __shared__ int ws[4];
    if (lane == 63) ws[wid] = inc;
    __syncthreads();
    int woff = 0;
    for (int w = 0; w < wid; ++w) woff += ws[w];
    if (t < nb) bsum[t] = woff + inc - v;
    if (t == 255) *rowptrN = woff + inc;
}

// Phase C: block-local exclusive scan + block offset -> rowptr, cursor
__global__ __launch_bounds__(256) void scan_final(const int* __restrict__ deg,
                                                  const int* __restrict__ bsum,
                                                  int* __restrict__ rowptr,
                                                  int* __restrict__ cursor, int N) {
    const int i = blockIdx.x * 256 + threadIdx.x;
    const int t = threadIdx.x;
    const int lane = t & 63, wid = t >> 6;
    int v = (i < N) ? deg[i] : 0;
    int inc = v;
    #pragma unroll
    for (int off = 1; off < 64; off <<= 1) {
        int u = __shfl_up(inc, off);
        if (lane >= off) inc += u;
    }
    __shared__ int ws[4];
    if (lane == 63) ws[wid] = inc;
    __syncthreads();
    int woff = 0;
    for (int w = 0; w < wid; ++w) woff += ws[w];
    const int excl = bsum[blockIdx.x] + woff + inc - v;
    if (i < N) { rowptr[i] = excl; cursor[i] = excl; }
}

__global__ void build_csr(const int* __restrict__ src, const int* __restrict__ dst,
                          int* __restrict__ cursor, int* __restrict__ csr_src, int E) {
    int e = blockIdx.x * blockDim.x + threadIdx.x;
    if (e < E) {
        int pos = atomicAdd(&cursor[dst[e]], 1);
        csr_src[pos] = src[e];
    }
}

// ---------------- bf16 MFMA GEMM: H = X @ Wt^T ----------------
__global__ __launch_bounds__(256) void gemm_bf16(
    const u16* __restrict__ X, const u16* __restrict__ Wt,
    u16* __restrict__ H, int N, int K, int NO)
{
    __shared__ unsigned char lds[33792];
    const int tid = threadIdx.x;
    const int w = tid >> 6;
    const int lane = tid & 63;
    const int m0 = blockIdx.x * 128;
    const int n0 = blockIdx.y * 128;

    f32x4 acc[4][4] = {};

    int gcol[2];
    int agrow[2], bgrow[2];
    #pragma unroll
    for (int i = 0; i < 2; ++i) {
        int idx = i * 256 + tid;
        int r = idx >> 2;
        int s = (idx & 3) ^ (r & 3);
        gcol[i] = s * 8;
        int ag = m0 + r; if (ag >= N) ag = N - 1;
        agrow[i] = ag;
        bgrow[i] = n0 + r;
    }

    for (int k0 = 0; k0 < K; k0 += 32) {
        #pragma unroll
        for (int i = 0; i < 2; ++i) {
            gload_lds16(X + (size_t)agrow[i] * K + k0 + gcol[i],
                        lds + i * 4096 + w * 1024);
            gload_lds16(Wt + (size_t)bgrow[i] * K + k0 + gcol[i],
                        lds + 8192 + i * 4096 + w * 1024);
        }
        asm volatile("s_waitcnt vmcnt(0)" ::: "memory");
        __syncthreads();

        bf16x8 af[4], bfr[4];
        #pragma unroll
        for (int m = 0; m < 4; ++m) {
            int r = (w >> 1) * 64 + m * 16 + (lane & 15);
            int off = r * 64 + (((lane >> 4) ^ (r & 3)) * 16);
            af[m] = *reinterpret_cast<const bf16x8*>(lds + off);
        }
        #pragma unroll
        for (int n = 0; n < 4; ++n) {
            int r = (w & 1) * 64 + n * 16 + (lane & 15);
            int off = 8192 + r * 64 + (((lane >> 4) ^ (r & 3)) * 16);
            bfr[n] = *reinterpret_cast<const bf16x8*>(lds + off);
        }
        #pragma unroll
        for (int m = 0; m < 4; ++m)
            #pragma unroll
            for (int n = 0; n < 4; ++n)
                acc[m][n] = __builtin_amdgcn_mfma_f32_16x16x32_bf16(
                    af[m], bfr[n], acc[m][n], 0, 0, 0);
        __syncthreads();
    }

    float* Cs = reinterpret_cast<float*>(lds);
    #pragma unroll
    for (int c = 0; c < 2; ++c) {
        __syncthreads();
        if ((w & 1) == c) {
            const int rbase = (w >> 1) * 64;
            #pragma unroll
            for (int m = 0; m < 4; ++m)
                #pragma unroll
                for (int n = 0; n < 4; ++n)
                    #pragma unroll
                    for (int r = 0; r < 4; ++r) {
                        int row = rbase + m * 16 + (lane >> 4) * 4 + r;
                        int col = n * 16 + (lane & 15);
                        Cs[row * 66 + col] = acc[m][n][r];
                    }
        }
        __syncthreads();
        const int row = tid >> 1;
        const int half = tid & 1;
        const int grow = m0 + row;
        if (grow < N) {
            const float* p = Cs + row * 66 + half * 32;
            bfu8 o0, o1, o2, o3;
            #pragma unroll
            for (int j = 0; j < 8; ++j) o0[j] = f2bf(p[j]);
            #pragma unroll
            for (int j = 0; j < 8; ++j) o1[j] = f2bf(p[8 + j]);
            #pragma unroll
            for (int j = 0; j < 8; ++j) o2[j] = f2bf(p[16 + j]);
            #pragma unroll
            for (int j = 0; j < 8; ++j) o3[j] = f2bf(p[24 + j]);
            bfu8* dst = reinterpret_cast<bfu8*>(H + (size_t)grow * NO + n0 + c * 64 + half * 32);
            dst[0] = o0; dst[1] = o1; dst[2] = o2; dst[3] = o3;
        }
    }
}

// ---------------- CSR pull-aggregate (bf16 H) ----------------
template <int F, int LPN, bool BFOUT, bool SUMOUT>
__global__ __launch_bounds__(256) void aggregate_bf(
    const u16* __restrict__ H, const int* __restrict__ rowptr,
    const int* __restrict__ csr_src, const float* __restrict__ dinv,
    const float* __restrict__ bias, void* __restrict__ Aout,
    float* __restrict__ partials, int N)
{
    constexpr int EPL = F / LPN;
    const int gtid = blockIdx.x * blockDim.x + threadIdx.x;
    const int node = gtid / LPN;
    const int lane = gtid - node * LPN;
    const int co = lane * EPL;
    const bool valid = node < N;

    float acc[EPL];
    #pragma unroll
    for (int q = 0; q < EPL; ++q) acc[q] = 0.f;

    if (valid) {
        const int beg = rowptr[node], end = rowptr[node + 1];
        for (int j = beg; j < end; ++j) {
            const int s = csr_src[j];
            const float ds = dinv[s];
            if constexpr (EPL == 8) {
                bfu8 v = *reinterpret_cast<const bfu8*>(H + (size_t)s * F + co);
                #pragma unroll
                for (int q = 0; q < 8; ++q) acc[q] = fmaf(bf2f(v[q]), ds, acc[q]);
            } else {
                bfu4 v = *reinterpret_cast<const bfu4*>(H + (size_t)s * F + co);
                #pragma unroll
                for (int q = 0; q < EPL; ++q) acc[q] = fmaf(bf2f(v[q]), ds, acc[q]);
            }
        }
    }

    float r[EPL];
    #pragma unroll
    for (int q = 0; q < EPL; ++q) r[q] = 0.f;
    if (valid) {
        const float dd = dinv[node], dd2 = dd * dd;
        if constexpr (EPL == 8) {
            bfu8 sv = *reinterpret_cast<const bfu8*>(H + (size_t)node * F + co);
            #pragma unroll
            for (int q = 0; q < 8; ++q)
                r[q] = fmaf(acc[q], dd, fmaf(bf2f(sv[q]), dd2, bias[co + q]));
        } else {
            bfu4 sv = *reinterpret_cast<const bfu4*>(H + (size_t)node * F + co);
            #pragma unroll
            for (int q = 0; q < EPL; ++q)
                r[q] = fmaf(acc[q], dd, fmaf(bf2f(sv[q]), dd2, bias[co + q]));
        }
    }

    if constexpr (BFOUT) {
        if (valid) {
            u16* out = reinterpret_cast<u16*>(Aout) + (size_t)node * F + co;
            if constexpr (EPL == 8) {
                bfu8 o;
                #pragma unroll
                for (int q = 0; q < 8; ++q) o[q] = f2bf(fmaxf(r[q], 0.f));
                *reinterpret_cast<bfu8*>(out) = o;
            } else {
                bfu4 o;
                #pragma unroll
                for (int q = 0; q < EPL; ++q) o[q] = f2bf(fmaxf(r[q], 0.f));
                *reinterpret_cast<bfu4*>(out) = o;
            }
        }
    } else if constexpr (SUMOUT) {
        float ls = 0.f;
        if (valid) {
            float* out = reinterpret_cast<float*>(Aout) + (size_t)node * F + co;
            #pragma unroll
            for (int q = 0; q < EPL; ++q) {
                const float z = fmaxf(r[q], 0.f);
                out[q] = z;
                ls += z;
            }
        }
        const int wl = threadIdx.x & 63, wi = threadIdx.x >> 6;
        #pragma unroll
        for (int off = 32; off; off >>= 1) ls += __shfl_down(ls, off);
        __shared__ float wsum[4];
        if (wl == 0) wsum[wi] = ls;
        __syncthreads();
        if (threadIdx.x == 0)
            partials[blockIdx.x] = wsum[0] + wsum[1] + wsum[2] + wsum[3];
    } else {
        if (valid) {
            float* out = reinterpret_cast<float*>(Aout) + (size_t)node * F + co;
            #pragma unroll
            for (int q = 0; q < EPL; ++q) out[q] = r[q];
        }
    }
}

// ---------------- epilogue ----------------
__global__ __launch_bounds__(1024) void reduce_partials(const float* __restrict__ partials,
                                                        float* __restrict__ S, int n) {
    float local = 0.f;
    for (int i = threadIdx.x; i < n; i += 1024) local += partials[i];
    const int lane = threadIdx.x & 63, wid = threadIdx.x >> 6;
    #pragma unroll
    for (int off = 32; off; off >>= 1) local += __shfl_down(local, off);
    __shared__ float wsum[16];
    if (lane == 0) wsum[wid] = local;
    __syncthreads();
    if (threadIdx.x == 0) {
        float t = 0.f;
        #pragma unroll
        for (int i = 0; i < 16; ++i) t += wsum[i];
        *S = t;
    }
}

__global__ void final_norm(float* __restrict__ Z, const float* __restrict__ S, int N) {
    const int wid = threadIdx.x >> 6;
    const int lane = threadIdx.x & 63;
    const int row = blockIdx.x * 4 + wid;
    if (row >= N) return;
    const float inv = 1.0f / (*S);
    float v0 = Z[(size_t)row * 128 + lane] * inv;
    float v1 = Z[(size_t)row * 128 + lane + 64] * inv;
    const float t0 = tanhf(v0), t1 = tanhf(v1);
    const float y0 = t0 * t0, y1 = t1 * t1;
    float ss = y0 * y0 + y1 * y1;
    #pragma unroll
    for (int off = 32; off; off >>= 1) ss += __shfl_xor(ss, off);
    const float nrm = fmaxf(sqrtf(ss), 1e-12f);
    const float innrm = 1.0f / nrm;
    Z[(size_t)row * 128 + lane]      = y0 * innrm;
    Z[(size_t)row * 128 + lane + 64] = y1 * innrm;
}

extern "C" void kernel_launch(void* const* d_in, const int* in_sizes, int n_in,
                              void* d_out, int out_size, void* d_ws, size_t ws_size,
                              hipStream_t stream) {
    const float* x  = (const float*)d_in[0];
    const int*   ei = (const int*)d_in[1];
    const float* W1 = (const float*)d_in[2];
    const float* b1 = (const float*)d_in[3];
    const float* W2 = (const float*)d_in[4];
    const float* b2 = (const float*)d_in[5];
    const float* W3 = (const float*)d_in[6];
    const float* b3 = (const float*)d_in[7];
    float* out = (float*)d_out;

    const int N = NN, E = NE;
    const int* src = ei;
    const int* dst = ei + E;

    char* ws = (char*)d_ws;
    size_t off = 0;
    u16* bufA = (u16*)(ws + off); off += (size_t)N * 512 * 2;
    u16* bufB = (u16*)(ws + off); off += (size_t)N * 512 * 2;
    u16* Wt1 = (u16*)(ws + off); off += 512 * 512 * 2;
    u16* Wt2 = (u16*)(ws + off); off += 256 * 512 * 2;
    u16* Wt3 = (u16*)(ws + off); off += 128 * 256 * 2;
    float* dinv   = (float*)(ws + off); off += 204800;
    int*   deg    = (int*)  (ws + off); off += 204800;
    int*   rowptr = (int*)  (ws + off); off += 204800;
    int*   cursor = (int*)  (ws + off); off += 204800;
    int*   bsum   = (int*)  (ws + off); off += 4096;
    float* Ssum   = (float*)(ws + off); off += 256;
    float* partials = (float*)(ws + off); off += 32768;
    int*   csr    = (int*)  (ws + off); off += (size_t)E * 4;

    // ---- conversions ----
    cvt_f32_bf16<<<(N * 512 / 4 + 255) / 256, 256, 0, stream>>>(x, bufA, N * 512 / 4);
    transpose_w<<<(512 * 512 + 255) / 256, 256, 0, stream>>>(W1, Wt1, 512, 512);
    transpose_w<<<(512 * 256 + 255) / 256, 256, 0, stream>>>(W2, Wt2, 512, 256);
    transpose_w<<<(256 * 128 + 255) / 256, 256, 0, stream>>>(W3, Wt3, 256, 128);

    // ---- CSR + dinv ----
    const int NB = (N + 255) / 256;   // 196
    zero_int<<<(N + 255) / 256, 256, 0, stream>>>(deg, N);
    edge_hist<<<(E + 255) / 256, 256, 0, stream>>>(dst, deg, E);
    deg_block_sum<<<NB, 256, 0, stream>>>(deg, dinv, bsum, N);
    scan_bsums<<<1, 256, 0, stream>>>(bsum, rowptr + N, NB);
    scan_final<<<NB, 256, 0, stream>>>(deg, bsum, rowptr, cursor, N);
    build_csr<<<(E + 255) / 256, 256, 0, stream>>>(src, dst, cursor, csr, E);

    const int MT = (N + 127) / 128;
    // ---- layer 1 ----
    gemm_bf16<<<dim3(MT, 4), 256, 0, stream>>>(bufA, Wt1, bufB, N, 512, 512);
    aggregate_bf<512, 64, true, false><<<(N * 64 + 255) / 256, 256, 0, stream>>>(
        bufB, rowptr, csr, dinv, b1, bufA, nullptr, N);
    // ---- layer 2 ----
    gemm_bf16<<<dim3(MT, 2), 256, 0, stream>>>(bufA, Wt2, bufB, N, 512, 256);
    aggregate_bf<256, 64, true, false><<<(N * 64 + 255) / 256, 256, 0, stream>>>(
        bufB, rowptr, csr, dinv, b2, bufA, nullptr, N);
    // ---- layer 3 ----
    gemm_bf16<<<dim3(MT, 1), 256, 0, stream>>>(bufA, Wt3, bufB, N, 256, 128);
    const int aggBlocks3 = (N * 32 + 255) / 256;
    aggregate_bf<128, 32, false, true><<<aggBlocks3, 256, 0, stream>>>(
        bufB, rowptr, csr, dinv, b3, out, partials, N);

    // ---- epilogue ----
    reduce_partials<<<1, 1024, 0, stream>>>(partials, Ssum, aggBlocks3);
    final_norm<<<(N + 3) / 4, 256, 0, stream>>>(out, Ssum, N);
}